// Round 10
// baseline (576.931 us; speedup 1.0000x reference)
//
#include <hip/hip_runtime.h>

#define N_NODES 50000
#define E_EDGES 800000
#define NFEAT   512
#define NHID    256
#define NCLS    100
#define LN_EPS  1e-5f

#define NB     196     // row buckets of 256 rows
#define CHUNKA 6144    // edges per bin-pass block
#define CAPB   6656    // slots per bucket (exp 4096, +40 sigma)

typedef __attribute__((ext_vector_type(8))) short bf16x8;
typedef __attribute__((ext_vector_type(4))) float f32x4;

__device__ __forceinline__ ushort bf16_rne(float x) {
    unsigned u = __float_as_uint(x);
    unsigned r = u + 0x7FFFu + ((u >> 16) & 1u);
    return (ushort)(r >> 16);
}
__device__ __forceinline__ float bf16_to_f(ushort h) {
    return __uint_as_float(((unsigned)h) << 16);
}

// async global->LDS, 16 B per lane; LDS dest = wave-uniform base + lane*16
__device__ __forceinline__ void gload16(const void* g, void* l) {
    __builtin_amdgcn_global_load_lds(
        (const __attribute__((address_space(1))) unsigned int*)g,
        (__attribute__((address_space(3))) unsigned int*)l, 16, 0, 0);
}

// ---------------------------------------------------------------------------
// All 5 weight transposes in one launch: W [K][Nc] fp32 -> WT [NP][K] bf16
// ---------------------------------------------------------------------------
__global__ __launch_bounds__(256)
void wsplit_all(const float* __restrict__ W0, const float* __restrict__ W1,
                const float* __restrict__ W2, const float* __restrict__ W3,
                const float* __restrict__ Wo,
                ushort* __restrict__ W0T, ushort* __restrict__ W1T,
                ushort* __restrict__ W2T, ushort* __restrict__ W3T,
                ushort* __restrict__ WoT)
{
    int idx = blockIdx.x * 256 + threadIdx.x;
    const float* W; ushort* WT; int K, Nc;
    if      (idx < 131072) { W = W0; WT = W0T; K = 512; Nc = 256; }
    else if (idx < 262144) { idx -= 131072; W = W1; WT = W1T; K = 512; Nc = 256; }
    else if (idx < 327680) { idx -= 262144; W = W2; WT = W2T; K = 256; Nc = 256; }
    else if (idx < 458752) { idx -= 327680; W = W3; WT = W3T; K = 512; Nc = 256; }
    else if (idx < 491520) { idx -= 458752; W = Wo; WT = WoT; K = 256; Nc = 100; }
    else return;
    const int n = idx / K, k = idx - n * K;
    WT[idx] = bf16_rne((n < Nc) ? W[(size_t)k * Nc + n] : 0.f);
}

// ---------------------------------------------------------------------------
// x fp32 -> bf16 (streaming), 8 elems/thread
// ---------------------------------------------------------------------------
__global__ __launch_bounds__(256)
void xconv_kernel(const float* __restrict__ x, ushort* __restrict__ xb, int n8)
{
    const int idx = blockIdx.x * 256 + threadIdx.x;
    if (idx >= n8) return;
    const float4 v0 = ((const float4*)x)[idx * 2];
    const float4 v1 = ((const float4*)x)[idx * 2 + 1];
    bf16x8 h;
    h[0] = (short)bf16_rne(v0.x); h[1] = (short)bf16_rne(v0.y);
    h[2] = (short)bf16_rne(v0.z); h[3] = (short)bf16_rne(v0.w);
    h[4] = (short)bf16_rne(v1.x); h[5] = (short)bf16_rne(v1.y);
    h[6] = (short)bf16_rne(v1.z); h[7] = (short)bf16_rne(v1.w);
    *(bf16x8*)&xb[idx * 8] = h;
}

// ---------------------------------------------------------------------------
// bf16 MFMA GEMM: 128x128 tile, BK=32, 256 thr = 4 waves (2x2), wave tile
// 64x64 (4x4 frags, 16 MFMA / 8 ds_read per step). Double-buffered LDS,
// prefetch-before-compute, 1 barrier/step, XOR-swizzled gload src + ds_read.
// ---------------------------------------------------------------------------
template<int WF32, int WBF>
__global__ __launch_bounds__(256)
void gemm_mfma_bf16(const ushort* __restrict__ A1, const ushort* __restrict__ A2,
                    int K1, int K, const ushort* __restrict__ BT,
                    const float* __restrict__ bias, float* __restrict__ C,
                    ushort* __restrict__ Cbf, int M, int Nc)
{
    __shared__ __align__(16) ushort Ah[2][128 * 32];
    __shared__ __align__(16) ushort Bh[2][128 * 32];

    const int tid = threadIdx.x;
    const int bm  = blockIdx.x * 128;
    const int bn  = blockIdx.y * 128;
    const int w   = tid >> 6;          // wave 0..3
    const int l   = tid & 63;
    const int wm  = (w >> 1) * 64;     // 0 / 64
    const int wn  = (w & 1) * 64;      // 0 / 64
    const int fr  = l & 15;
    const int fq  = l >> 4;

    const int gro = l >> 2;                        // 0..15
    const int gch = ((l & 3) ^ (gro & 3)) * 8;     // swizzled ushort offset
    const int ldsbase = (32 * w) * 32;             // wave stages rows 32w..32w+31

    f32x4 acc[4][4];
    #pragma unroll
    for (int i = 0; i < 4; ++i)
        #pragma unroll
        for (int j = 0; j < 4; ++j) acc[i][j] = (f32x4){0.f, 0.f, 0.f, 0.f};

    const int K2 = K - K1;
    const int NS = K / 32;

    auto stage = [&](int s, int b) {
        const int k0 = s * 32;
        gload16(&BT[(size_t)(bn + 32 * w + gro) * K + k0 + gch],      &Bh[b][ldsbase]);
        gload16(&BT[(size_t)(bn + 32 * w + 16 + gro) * K + k0 + gch], &Bh[b][ldsbase + 512]);
        const ushort *a0, *a1;
        if (k0 < K1) {
            a0 = &A1[(size_t)(bm + 32 * w + gro) * K1 + k0 + gch];
            a1 = &A1[(size_t)(bm + 32 * w + 16 + gro) * K1 + k0 + gch];
        } else {
            a0 = &A2[(size_t)(bm + 32 * w + gro) * K2 + (k0 - K1) + gch];
            a1 = &A2[(size_t)(bm + 32 * w + 16 + gro) * K2 + (k0 - K1) + gch];
        }
        gload16(a0, &Ah[b][ldsbase]);
        gload16(a1, &Ah[b][ldsbase + 512]);
    };

    stage(0, 0);
    __syncthreads();

    int cur = 0;
    for (int s = 0; s < NS; ++s) {
        if (s + 1 < NS) stage(s + 1, cur ^ 1);   // prefetch overlaps compute

        bf16x8 bf[4];
        #pragma unroll
        for (int nf = 0; nf < 4; ++nf) {
            const int r = wn + nf * 16 + fr;
            bf[nf] = *(const bf16x8*)&Bh[cur][r * 32 + ((fq ^ (r & 3)) * 8)];
        }
        #pragma unroll
        for (int mf = 0; mf < 4; ++mf) {
            const int r = wm + mf * 16 + fr;
            const bf16x8 af = *(const bf16x8*)&Ah[cur][r * 32 + ((fq ^ (r & 3)) * 8)];
            #pragma unroll
            for (int nf = 0; nf < 4; ++nf)
                acc[mf][nf] = __builtin_amdgcn_mfma_f32_16x16x32_bf16(af, bf[nf], acc[mf][nf], 0, 0, 0);
        }
        __syncthreads();   // drains prefetch + guards buffer reuse
        cur ^= 1;
    }

    // epilogue: D col = lane&15, row = (lane>>4)*4 + reg
    #pragma unroll
    for (int mf = 0; mf < 4; ++mf) {
        #pragma unroll
        for (int r = 0; r < 4; ++r) {
            const int row = bm + wm + mf * 16 + fq * 4 + r;
            if (row >= M) continue;
            #pragma unroll
            for (int nf = 0; nf < 4; ++nf) {
                const int col = bn + wn + nf * 16 + fr;
                if (col < Nc) {
                    const float v = acc[mf][nf][r] + bias[col];
                    if (WF32) C[(size_t)row * Nc + col] = v;
                    if (WBF)  Cbf[(size_t)row * Nc + col] = bf16_rne(v);
                }
            }
        }
    }
}

// ---------------------------------------------------------------------------
// CSR build: bin -> bucket scan -> sort (writes rowstart)
// ---------------------------------------------------------------------------
__global__ __launch_bounds__(256)
void bin_kernel(const int* __restrict__ rows, const int* __restrict__ cols,
                const float* __restrict__ vals, int* __restrict__ bcur,
                int2* __restrict__ est)
{
    __shared__ int cnt[NB];
    __shared__ int scn[256];
    __shared__ int cstart[NB];
    __shared__ int ccur[NB];
    __shared__ int garr[NB];
    __shared__ __align__(16) int2 buf[CHUNKA];

    const int a  = blockIdx.y;
    const int e0 = blockIdx.x * CHUNKA;
    const int n  = min(CHUNKA, E_EDGES - e0);
    const int t  = threadIdx.x;
    const int*   rp = rows + (size_t)a * E_EDGES + e0;
    const int*   cp = cols + (size_t)a * E_EDGES + e0;
    const float* vp = vals + (size_t)a * E_EDGES + e0;

    if (t < NB) cnt[t] = 0;
    __syncthreads();
    for (int i = t; i < n; i += 256) atomicAdd(&cnt[((unsigned)rp[i]) >> 8], 1);
    __syncthreads();

    scn[t] = (t < NB) ? cnt[t] : 0;
    __syncthreads();
    for (int off = 1; off < 256; off <<= 1) {
        const int v = (t >= off) ? scn[t - off] : 0;
        __syncthreads();
        scn[t] += v;
        __syncthreads();
    }
    if (t < NB) {
        const int ex = scn[t] - cnt[t];
        cstart[t] = ex;
        ccur[t]   = ex;
        garr[t]   = atomicAdd(&bcur[a * NB + t], cnt[t]);
    }
    __syncthreads();

    for (int i = t; i < n; i += 256) {
        const unsigned r = (unsigned)rp[i];
        const int b = r >> 8;
        const int p = atomicAdd(&ccur[b], 1);
        buf[p] = make_int2((int)((r << 16) | (unsigned)cp[i]), __float_as_int(vp[i]));
    }
    __syncthreads();

    for (int i = t; i < n; i += 256) {
        const int2 en = buf[i];
        const int b = ((unsigned)en.x) >> 24;
        const int slot = garr[b] + (i - cstart[b]);
        if (slot < CAPB)
            est[((size_t)(a * NB + b)) * CAPB + slot] = en;
    }
}

__global__ __launch_bounds__(256)
void bscan_kernel(const int* __restrict__ bcur, int* __restrict__ bbase)
{
    __shared__ int s[256];
    const int a = blockIdx.x;
    const int t = threadIdx.x;
    const int v = (t < NB) ? bcur[a * NB + t] : 0;
    s[t] = v;
    __syncthreads();
    for (int off = 1; off < 256; off <<= 1) {
        const int u = (t >= off) ? s[t - off] : 0;
        __syncthreads();
        s[t] += u;
        __syncthreads();
    }
    if (t < NB) bbase[a * NB + t] = s[t] - v;
}

// Two-pass counting sort per bucket: pass1 counts from L2, pass2 scatters
// directly into obuf (no sbuf copy) -> 56 KB LDS, 2 blocks/CU.
__global__ __launch_bounds__(256)
void sort_kernel(const int* __restrict__ bcur, const int* __restrict__ bbase,
                 const int2* __restrict__ est, int2* __restrict__ cpk,
                 int* __restrict__ rowstart)
{
    __shared__ __align__(16) int2 obuf[CAPB];
    __shared__ int cnt[256];
    __shared__ int cur[256];

    const int a = blockIdx.y;
    const int b = blockIdx.x;
    const int t = threadIdx.x;
    const int nb = min(bcur[a * NB + b], CAPB);
    const int2* ei = est + ((size_t)(a * NB + b)) * CAPB;

    cnt[t] = 0;
    __syncthreads();
    for (int i = t; i < nb; i += 256)
        atomicAdd(&cnt[(((unsigned)ei[i].x) >> 16) & 255], 1);
    __syncthreads();

    int scv = cnt[t];
    // Hillis-Steele over cnt via cur as scratch
    cur[t] = scv;
    __syncthreads();
    for (int off = 1; off < 256; off <<= 1) {
        const int v = (t >= off) ? cur[t - off] : 0;
        __syncthreads();
        cur[t] += v;
        __syncthreads();
    }
    const int excl = cur[t] - scv;
    __syncthreads();
    cur[t] = excl;

    const int bb = bbase[a * NB + b];
    const int r0 = b << 8;
    if (r0 + t < N_NODES)
        rowstart[(size_t)a * (N_NODES + 1) + r0 + t] = bb + excl;
    if (b == NB - 1 && t == 0)
        rowstart[(size_t)a * (N_NODES + 1) + N_NODES] = E_EDGES;
    __syncthreads();

    for (int i = t; i < nb; i += 256) {
        const int2 en = ei[i];
        const int r = (((unsigned)en.x) >> 16) & 255;
        const int p = atomicAdd(&cur[r], 1);
        obuf[p] = make_int2(en.x & 0xFFFF, en.y);
    }
    __syncthreads();

    int2* co = cpk + (size_t)a * E_EDGES + bb;
    for (int i = t; i < nb; i += 256) co[i] = obuf[i];
}

// ---------------------------------------------------------------------------
// SpMM gather over CSR, scalar edge loads (wave-uniform -> s_load broadcast).
// One wave per row; lane holds 4 bf16 (8 B).
// LNFUSE=1: fused LayerNorm over concat [feat[row] | agg] + affine + relu.
// ---------------------------------------------------------------------------
template<int LNFUSE>
__global__ __launch_bounds__(256)
void spmm_kernel(const int* __restrict__ rowstart, const int2* __restrict__ cpk,
                 const ushort* __restrict__ feat, ushort* __restrict__ out0,
                 ushort* __restrict__ out1, const float* __restrict__ g,
                 const float* __restrict__ be)
{
    const int row  = __builtin_amdgcn_readfirstlane((blockIdx.x * 256 + threadIdx.x) >> 6);
    const int lane = threadIdx.x & 63;

    const int s = __builtin_amdgcn_readfirstlane(rowstart[row]);
    const int e = __builtin_amdgcn_readfirstlane(rowstart[row + 1]);

    const ushort* fbase = feat + lane * 4;
    float ax = 0.f, ay = 0.f, az = 0.f, aw = 0.f;

    for (int j = s; j < e; j += 16) {
        #pragma unroll
        for (int q = 0; q < 16; ++q) {
            if (j + q < e) {                       // uniform branch
                const int2 ev = cpk[j + q];        // scalar load + broadcast
                const float v = __int_as_float(ev.y);
                const uint2 f = *(const uint2*)(fbase + (size_t)ev.x * NHID);
                ax += v * __uint_as_float(f.x << 16);
                ay += v * __uint_as_float(f.x & 0xFFFF0000u);
                az += v * __uint_as_float(f.y << 16);
                aw += v * __uint_as_float(f.y & 0xFFFF0000u);
            }
        }
    }

    if (LNFUSE) {
        const uint2 fx = *(const uint2*)(fbase + (size_t)row * NHID);
        float xf[4] = {__uint_as_float(fx.x << 16), __uint_as_float(fx.x & 0xFFFF0000u),
                       __uint_as_float(fx.y << 16), __uint_as_float(fx.y & 0xFFFF0000u)};

        float sum = xf[0] + xf[1] + xf[2] + xf[3] + ax + ay + az + aw;
        #pragma unroll
        for (int m = 1; m < 64; m <<= 1) sum += __shfl_xor(sum, m, 64);
        const float mean = sum * (1.f / 512.f);

        float sq = 0.f;
        #pragma unroll
        for (int jj = 0; jj < 4; ++jj) { const float d = xf[jj] - mean; sq += d * d; }
        { float d; d = ax - mean; sq += d * d; d = ay - mean; sq += d * d;
          d = az - mean; sq += d * d; d = aw - mean; sq += d * d; }
        #pragma unroll
        for (int m = 1; m < 64; m <<= 1) sq += __shfl_xor(sq, m, 64);
        const float rstd = rsqrtf(sq * (1.f / 512.f) + LN_EPS);

        const int col = lane * 4;
        const float av[4] = {ax, ay, az, aw};
        ushort4 o0, o1;
        float t0[4], t1[4];
        #pragma unroll
        for (int jj = 0; jj < 4; ++jj) {
            t0[jj] = fmaxf((xf[jj] - mean) * rstd * g[col + jj] + be[col + jj], 0.f);
            t1[jj] = fmaxf((av[jj] - mean) * rstd * g[256 + col + jj] + be[256 + col + jj], 0.f);
        }
        o0.x = bf16_rne(t0[0]); o0.y = bf16_rne(t0[1]); o0.z = bf16_rne(t0[2]); o0.w = bf16_rne(t0[3]);
        o1.x = bf16_rne(t1[0]); o1.y = bf16_rne(t1[1]); o1.z = bf16_rne(t1[2]); o1.w = bf16_rne(t1[3]);
        *(ushort4*)&out0[(size_t)row * NHID + col] = o0;
        *(ushort4*)&out1[(size_t)row * NHID + col] = o1;
    } else {
        ushort4 o;
        o.x = bf16_rne(fmaxf(ax, 0.f)); o.y = bf16_rne(fmaxf(ay, 0.f));
        o.z = bf16_rne(fmaxf(az, 0.f)); o.w = bf16_rne(fmaxf(aw, 0.f));
        *(ushort4*)&out0[(size_t)row * NHID + lane * 4] = o;
    }
}

// ---------------------------------------------------------------------------
extern "C" void kernel_launch(void* const* d_in, const int* in_sizes, int n_in,
                              void* d_out, int out_size, void* d_ws, size_t ws_size,
                              hipStream_t stream)
{
    const float* x    = (const float*)d_in[0];
    const int*   rows = (const int*)  d_in[1];
    const int*   cols = (const int*)  d_in[2];
    const float* vals = (const float*)d_in[3];
    const float* W0   = (const float*)d_in[4];
    const float* b0   = (const float*)d_in[5];
    const float* g0   = (const float*)d_in[6];
    const float* be0  = (const float*)d_in[7];
    const float* W1   = (const float*)d_in[8];
    const float* b1   = (const float*)d_in[9];
    const float* W2   = (const float*)d_in[10];
    const float* b2   = (const float*)d_in[11];
    const float* g2   = (const float*)d_in[12];
    const float* be2  = (const float*)d_in[13];
    const float* W3   = (const float*)d_in[14];
    const float* b3   = (const float*)d_in[15];
    const float* Wout = (const float*)d_in[16];
    const float* bout = (const float*)d_in[17];
    float* out = (float*)d_out;

    // ---- workspace carve ----
    char* wsb = (char*)d_ws;
    size_t off = 0;
    auto carve = [&](size_t bytes) { void* p = wsb + off; off += (bytes + 255) & ~(size_t)255; return p; };
    int*    rowstart = (int*)   carve((size_t)4 * (N_NODES + 1) * 4);
    int*    bcur     = (int*)   carve((size_t)4 * NB * 4);
    int*    bbase    = (int*)   carve((size_t)4 * NB * 4);
    int2*   cpk      = (int2*)  carve((size_t)4 * E_EDGES * 8);
    int2*   est      = (int2*)  carve((size_t)4 * NB * CAPB * 8);
    ushort* Xb       = (ushort*)carve((size_t)N_NODES * NFEAT * 2);   // bf16 x
    ushort* F        = (ushort*)carve((size_t)N_NODES * NHID * 2);    // feat
    ushort* P        = (ushort*)carve((size_t)N_NODES * NHID * 2);    // LN feat half
    ushort* Q        = (ushort*)carve((size_t)N_NODES * NHID * 2);    // LN agg half
    ushort* G        = (ushort*)carve((size_t)N_NODES * NHID * 2);    // GCN lin out
    ushort* H        = (ushort*)carve((size_t)N_NODES * NHID * 2);    // GCN relu(agg)
    ushort* W0T = (ushort*)carve((size_t)256 * 512 * 2);
    ushort* W1T = (ushort*)carve((size_t)256 * 512 * 2);
    ushort* W2T = (ushort*)carve((size_t)256 * 256 * 2);
    ushort* W3T = (ushort*)carve((size_t)256 * 512 * 2);
    ushort* WoT = (ushort*)carve((size_t)128 * 256 * 2);
    carve(131072);   // guard pad (gload A-tail overreads)

    const dim3 blk(256);
    const dim3 g_gemm(391, 2);
    const dim3 g_head(391, 1);
    const dim3 g_bin((E_EDGES + CHUNKA - 1) / CHUNKA, 4);   // (131, 4)
    const dim3 g_sort(NB, 4);                               // (196, 4)
    const int  row_blocks = (N_NODES * 64 + 255) / 256;     // 12500

    // ---- weight transpose + x convert ----
    wsplit_all<<<1920, blk, 0, stream>>>(W0, W1, W2, W3, Wout, W0T, W1T, W2T, W3T, WoT);
    xconv_kernel<<<(N_NODES * NFEAT / 8 + 255)/256, blk, 0, stream>>>(x, Xb, N_NODES * NFEAT / 8);

    // ---- CSR build: bin -> bucket scan -> sort (writes rowstart) ----
    hipMemsetAsync(bcur, 0, (size_t)4 * NB * 4, stream);
    bin_kernel<<<g_bin, blk, 0, stream>>>(rows, cols, vals, bcur, est);
    bscan_kernel<<<4, blk, 0, stream>>>(bcur, bbase);
    sort_kernel<<<g_sort, blk, 0, stream>>>(bcur, bbase, est, cpk, rowstart);

    const int* rs0 = rowstart;
    const int* rs1 = rowstart + (N_NODES + 1);
    const int* rs2 = rowstart + 2 * (N_NODES + 1);
    const int* rs3 = rowstart + 3 * (N_NODES + 1);
    const int2* c0 = cpk;
    const int2* c1 = cpk + E_EDGES;
    const int2* c2 = cpk + 2 * (size_t)E_EDGES;
    const int2* c3 = cpk + 3 * (size_t)E_EDGES;

    // ---- layer 0: GraphSage(512->256): Xb -> F; spmm+LN -> P,Q ----
    gemm_mfma_bf16<0,1><<<g_gemm, blk, 0, stream>>>(Xb, Xb, 512, 512, W0T, b0, nullptr, F, N_NODES, 256);
    spmm_kernel<1><<<row_blocks, blk, 0, stream>>>(rs0, c0, F, P, Q, g0, be0);

    // ---- layer 1: GCN(concat [P|Q] 512->256) -> G; spmm+relu -> H ----
    gemm_mfma_bf16<0,1><<<g_gemm, blk, 0, stream>>>(P, Q, 256, 512, W1T, b1, nullptr, G, N_NODES, 256);
    spmm_kernel<0><<<row_blocks, blk, 0, stream>>>(rs1, c1, G, H, nullptr, nullptr, nullptr);

    // ---- layer 2: GraphSage(256->256): H -> F; spmm+LN -> P,Q ----
    gemm_mfma_bf16<0,1><<<g_gemm, blk, 0, stream>>>(H, H, 256, 256, W2T, b2, nullptr, F, N_NODES, 256);
    spmm_kernel<1><<<row_blocks, blk, 0, stream>>>(rs2, c2, F, P, Q, g2, be2);

    // ---- layer 3: GCN(concat [P|Q] 512->256) -> G; spmm+relu -> H ----
    gemm_mfma_bf16<0,1><<<g_gemm, blk, 0, stream>>>(P, Q, 256, 512, W3T, b3, nullptr, G, N_NODES, 256);
    spmm_kernel<0><<<row_blocks, blk, 0, stream>>>(rs3, c3, G, H, nullptr, nullptr, nullptr);

    // ---- output head: H @ WoT + bout -> out (fp32) ----
    gemm_mfma_bf16<1,0><<<g_head, blk, 0, stream>>>(H, H, 256, 256, WoT, bout, out, nullptr, N_NODES, 100);
}

// Round 12
// 484.472 us; speedup vs baseline: 1.1908x; 1.1908x over previous
//
#include <hip/hip_runtime.h>

#define N_NODES 50000
#define E_EDGES 800000
#define NFEAT   512
#define NHID    256
#define NCLS    100
#define LN_EPS  1e-5f

#define NB     196     // row buckets of 256 rows
#define CHUNKA 6144    // edges per bin-pass block
#define CAPB   6656    // slots per bucket (exp 4096, +40 sigma)

// prep_kernel section sizes (derived, not hard-coded)
#define WT_TOTAL  (256*512 + 256*512 + 256*256 + 256*512 + 128*256)   // 491520
#define XC_TOTAL  (N_NODES * NFEAT / 8)                               // 3200000
#define PREP_TOTAL (WT_TOTAL + XC_TOTAL + 4 * NB)

typedef __attribute__((ext_vector_type(8))) short bf16x8;
typedef __attribute__((ext_vector_type(4))) float f32x4;

__device__ __forceinline__ ushort bf16_rne(float x) {
    unsigned u = __float_as_uint(x);
    unsigned r = u + 0x7FFFu + ((u >> 16) & 1u);
    return (ushort)(r >> 16);
}
__device__ __forceinline__ float bf16_to_f(ushort h) {
    return __uint_as_float(((unsigned)h) << 16);
}

// async global->LDS, 16 B per lane; LDS dest = wave-uniform base + lane*16
__device__ __forceinline__ void gload16(const void* g, void* l) {
    __builtin_amdgcn_global_load_lds(
        (const __attribute__((address_space(1))) unsigned int*)g,
        (__attribute__((address_space(3))) unsigned int*)l, 16, 0, 0);
}

// ---------------------------------------------------------------------------
// prep: all 5 weight transposes + x fp32->bf16 + bcur zeroing, one launch.
// ---------------------------------------------------------------------------
__global__ __launch_bounds__(256)
void prep_kernel(const float* __restrict__ W0, const float* __restrict__ W1,
                 const float* __restrict__ W2, const float* __restrict__ W3,
                 const float* __restrict__ Wo, const float* __restrict__ x,
                 ushort* __restrict__ W0T, ushort* __restrict__ W1T,
                 ushort* __restrict__ W2T, ushort* __restrict__ W3T,
                 ushort* __restrict__ WoT, ushort* __restrict__ Xb,
                 int* __restrict__ bcur)
{
    int idx = blockIdx.x * 256 + threadIdx.x;
    if (idx < WT_TOTAL) {   // weight transposes
        const float* W; ushort* WT; int K, Nc;
        if      (idx < 131072) { W = W0; WT = W0T; K = 512; Nc = 256; }
        else if (idx < 262144) { idx -= 131072; W = W1; WT = W1T; K = 512; Nc = 256; }
        else if (idx < 327680) { idx -= 262144; W = W2; WT = W2T; K = 256; Nc = 256; }
        else if (idx < 458752) { idx -= 327680; W = W3; WT = W3T; K = 512; Nc = 256; }
        else                   { idx -= 458752; W = Wo; WT = WoT; K = 256; Nc = 100; }
        const int n = idx / K, k = idx - n * K;
        WT[idx] = bf16_rne((n < Nc) ? W[(size_t)k * Nc + n] : 0.f);
        return;
    }
    idx -= WT_TOTAL;
    if (idx < XC_TOTAL) {   // xconv: 8 elems/thread over N*NFEAT
        const float4 v0 = ((const float4*)x)[idx * 2];
        const float4 v1 = ((const float4*)x)[idx * 2 + 1];
        bf16x8 h;
        h[0] = (short)bf16_rne(v0.x); h[1] = (short)bf16_rne(v0.y);
        h[2] = (short)bf16_rne(v0.z); h[3] = (short)bf16_rne(v0.w);
        h[4] = (short)bf16_rne(v1.x); h[5] = (short)bf16_rne(v1.y);
        h[6] = (short)bf16_rne(v1.z); h[7] = (short)bf16_rne(v1.w);
        *(bf16x8*)&Xb[idx * 8] = h;
        return;
    }
    idx -= XC_TOTAL;
    if (idx < 4 * NB) bcur[idx] = 0;
}

// ---------------------------------------------------------------------------
// bf16 MFMA GEMM (R8 config): 128x128 tile, BK=32, 512 thr = 8 waves (2m x 4n),
// wave tile 64x32. Double-buffered LDS, prefetch-before-compute, 1 barrier/step,
// XOR-swizzled gload source + ds_read (both-sides rule).
// ---------------------------------------------------------------------------
template<int WF32, int WBF>
__global__ __launch_bounds__(512)
void gemm_mfma_bf16(const ushort* __restrict__ A1, const ushort* __restrict__ A2,
                    int K1, int K, const ushort* __restrict__ BT,
                    const float* __restrict__ bias, float* __restrict__ C,
                    ushort* __restrict__ Cbf, int M, int Nc)
{
    __shared__ __align__(16) ushort Ah[2][128 * 32];
    __shared__ __align__(16) ushort Bh[2][128 * 32];

    const int tid = threadIdx.x;
    const int bm  = blockIdx.x * 128;
    const int bn  = blockIdx.y * 128;
    const int w   = tid >> 6;          // wave 0..7
    const int l   = tid & 63;
    const int wm  = (w >> 2) * 64;     // 0 / 64
    const int wn  = (w & 3) * 32;      // 0,32,64,96
    const int fr  = l & 15;
    const int fq  = l >> 4;

    const int gro = l >> 2;                        // 0..15
    const int gch = ((l & 3) ^ (gro & 3)) * 8;     // swizzled ushort offset
    const int ldsbase = (16 * w) * 32;             // ushorts

    f32x4 acc[4][2];
    #pragma unroll
    for (int i = 0; i < 4; ++i) {
        acc[i][0] = (f32x4){0.f, 0.f, 0.f, 0.f};
        acc[i][1] = (f32x4){0.f, 0.f, 0.f, 0.f};
    }

    const int K2 = K - K1;
    const int NS = K / 32;

    auto stage = [&](int s, int b) {
        const int k0 = s * 32;
        gload16(&BT[(size_t)(bn + 16 * w + gro) * K + k0 + gch], &Bh[b][ldsbase]);
        const ushort* asrc;
        if (k0 < K1) asrc = &A1[(size_t)(bm + 16 * w + gro) * K1 + k0 + gch];
        else         asrc = &A2[(size_t)(bm + 16 * w + gro) * K2 + (k0 - K1) + gch];
        gload16(asrc, &Ah[b][ldsbase]);
    };

    stage(0, 0);
    __syncthreads();

    int cur = 0;
    for (int s = 0; s < NS; ++s) {
        if (s + 1 < NS) stage(s + 1, cur ^ 1);   // prefetch overlaps compute

        bf16x8 bf[2];
        #pragma unroll
        for (int nf = 0; nf < 2; ++nf) {
            const int r = wn + nf * 16 + fr;
            bf[nf] = *(const bf16x8*)&Bh[cur][r * 32 + ((fq ^ (r & 3)) * 8)];
        }
        #pragma unroll
        for (int mf = 0; mf < 4; ++mf) {
            const int r = wm + mf * 16 + fr;
            const bf16x8 af = *(const bf16x8*)&Ah[cur][r * 32 + ((fq ^ (r & 3)) * 8)];
            acc[mf][0] = __builtin_amdgcn_mfma_f32_16x16x32_bf16(af, bf[0], acc[mf][0], 0, 0, 0);
            acc[mf][1] = __builtin_amdgcn_mfma_f32_16x16x32_bf16(af, bf[1], acc[mf][1], 0, 0, 0);
        }
        __syncthreads();
        cur ^= 1;
    }

    #pragma unroll
    for (int mf = 0; mf < 4; ++mf) {
        #pragma unroll
        for (int r = 0; r < 4; ++r) {
            const int row = bm + wm + mf * 16 + fq * 4 + r;
            if (row >= M) continue;
            #pragma unroll
            for (int nf = 0; nf < 2; ++nf) {
                const int col = bn + wn + nf * 16 + fr;
                if (col < Nc) {
                    const float v = acc[mf][nf][r] + bias[col];
                    if (WF32) C[(size_t)row * Nc + col] = v;
                    if (WBF)  Cbf[(size_t)row * Nc + col] = bf16_rne(v);
                }
            }
        }
    }
}

// ---------------------------------------------------------------------------
// CSR build: bin -> sort (sort computes its bucket base inline, writes rowstart)
// ---------------------------------------------------------------------------
__global__ __launch_bounds__(256)
void bin_kernel(const int* __restrict__ rows, const int* __restrict__ cols,
                const float* __restrict__ vals, int* __restrict__ bcur,
                int2* __restrict__ est)
{
    __shared__ int cnt[NB];
    __shared__ int scn[256];
    __shared__ int cstart[NB];
    __shared__ int ccur[NB];
    __shared__ int garr[NB];
    __shared__ __align__(16) int2 buf[CHUNKA];

    const int a  = blockIdx.y;
    const int e0 = blockIdx.x * CHUNKA;
    const int n  = min(CHUNKA, E_EDGES - e0);
    const int t  = threadIdx.x;
    const int*   rp = rows + (size_t)a * E_EDGES + e0;
    const int*   cp = cols + (size_t)a * E_EDGES + e0;
    const float* vp = vals + (size_t)a * E_EDGES + e0;

    if (t < NB) cnt[t] = 0;
    __syncthreads();
    for (int i = t; i < n; i += 256) atomicAdd(&cnt[((unsigned)rp[i]) >> 8], 1);
    __syncthreads();

    scn[t] = (t < NB) ? cnt[t] : 0;
    __syncthreads();
    for (int off = 1; off < 256; off <<= 1) {
        const int v = (t >= off) ? scn[t - off] : 0;
        __syncthreads();
        scn[t] += v;
        __syncthreads();
    }
    if (t < NB) {
        const int ex = scn[t] - cnt[t];
        cstart[t] = ex;
        ccur[t]   = ex;
        garr[t]   = atomicAdd(&bcur[a * NB + t], cnt[t]);
    }
    __syncthreads();

    for (int i = t; i < n; i += 256) {
        const unsigned r = (unsigned)rp[i];
        const int b = r >> 8;
        const int p = atomicAdd(&ccur[b], 1);
        buf[p] = make_int2((int)((r << 16) | (unsigned)cp[i]), __float_as_int(vp[i]));
    }
    __syncthreads();

    for (int i = t; i < n; i += 256) {
        const int2 en = buf[i];
        const int b = ((unsigned)en.x) >> 24;
        const int slot = garr[b] + (i - cstart[b]);
        if (slot < CAPB)
            est[((size_t)(a * NB + b)) * CAPB + slot] = en;
    }
}

__global__ __launch_bounds__(256)
void sort_kernel(const int* __restrict__ bcur, const int2* __restrict__ est,
                 int2* __restrict__ cpk, int* __restrict__ rowstart)
{
    __shared__ __align__(16) int2 sbuf[CAPB];
    __shared__ __align__(16) int2 obuf[CAPB];
    __shared__ int cnt[256];
    __shared__ int scn[256];
    __shared__ int cur[256];

    const int a = blockIdx.y;
    const int b = blockIdx.x;
    const int t = threadIdx.x;
    const int nb = min(bcur[a * NB + b], CAPB);
    const int2* ei = est + ((size_t)(a * NB + b)) * CAPB;

    // bucket base bb = sum_{i<b} bcur[a*NB+i]  (block tree-reduce, b<=195)
    scn[t] = (t < b) ? bcur[a * NB + t] : 0;
    __syncthreads();
    for (int o = 128; o > 0; o >>= 1) {
        if (t < o) scn[t] += scn[t + o];
        __syncthreads();
    }
    const int bb = scn[0];
    __syncthreads();

    for (int i = t; i < nb; i += 256) sbuf[i] = ei[i];
    cnt[t] = 0;
    __syncthreads();
    for (int i = t; i < nb; i += 256)
        atomicAdd(&cnt[(((unsigned)sbuf[i].x) >> 16) & 255], 1);
    __syncthreads();

    scn[t] = cnt[t];
    __syncthreads();
    for (int off = 1; off < 256; off <<= 1) {
        const int v = (t >= off) ? scn[t - off] : 0;
        __syncthreads();
        scn[t] += v;
        __syncthreads();
    }
    const int excl = scn[t] - cnt[t];
    cur[t] = excl;

    const int r0 = b << 8;
    if (r0 + t < N_NODES)
        rowstart[(size_t)a * (N_NODES + 1) + r0 + t] = bb + excl;
    if (b == NB - 1 && t == 0)
        rowstart[(size_t)a * (N_NODES + 1) + N_NODES] = E_EDGES;
    __syncthreads();

    for (int i = t; i < nb; i += 256) {
        const int2 en = sbuf[i];
        const int r = (((unsigned)en.x) >> 16) & 255;
        const int p = atomicAdd(&cur[r], 1);
        obuf[p] = make_int2(en.x & 0xFFFF, en.y);
    }
    __syncthreads();

    int2* co = cpk + (size_t)a * E_EDGES + bb;
    for (int i = t; i < nb; i += 256) co[i] = obuf[i];
}

// ---------------------------------------------------------------------------
// SpMM gather over CSR, scalar edge loads (wave-uniform -> s_load broadcast).
// One wave per row; lane holds 4 bf16 (8 B). Full 16-batches unguarded.
// LNFUSE=1: fused LayerNorm over concat [feat[row] | agg] + affine + relu.
// ---------------------------------------------------------------------------
template<int LNFUSE>
__global__ __launch_bounds__(256)
void spmm_kernel(const int* __restrict__ rowstart, const int2* __restrict__ cpk,
                 const ushort* __restrict__ feat, ushort* __restrict__ out0,
                 ushort* __restrict__ out1, const float* __restrict__ g,
                 const float* __restrict__ be)
{
    const int row  = __builtin_amdgcn_readfirstlane((blockIdx.x * 256 + threadIdx.x) >> 6);
    const int lane = threadIdx.x & 63;

    const int s = __builtin_amdgcn_readfirstlane(rowstart[row]);
    const int e = __builtin_amdgcn_readfirstlane(rowstart[row + 1]);

    const ushort* fbase = feat + lane * 4;
    float ax = 0.f, ay = 0.f, az = 0.f, aw = 0.f;

    int j = s;
    for (; j + 16 <= e; j += 16) {
        #pragma unroll
        for (int q = 0; q < 16; ++q) {
            const int2 ev = cpk[j + q];            // scalar load + broadcast
            const float v = __int_as_float(ev.y);
            const uint2 f = *(const uint2*)(fbase + (size_t)ev.x * NHID);
            ax += v * __uint_as_float(f.x << 16);
            ay += v * __uint_as_float(f.x & 0xFFFF0000u);
            az += v * __uint_as_float(f.y << 16);
            aw += v * __uint_as_float(f.y & 0xFFFF0000u);
        }
    }
    for (; j < e; ++j) {
        const int2 ev = cpk[j];
        const float v = __int_as_float(ev.y);
        const uint2 f = *(const uint2*)(fbase + (size_t)ev.x * NHID);
        ax += v * __uint_as_float(f.x << 16);
        ay += v * __uint_as_float(f.x & 0xFFFF0000u);
        az += v * __uint_as_float(f.y << 16);
        aw += v * __uint_as_float(f.y & 0xFFFF0000u);
    }

    if (LNFUSE) {
        const uint2 fx = *(const uint2*)(fbase + (size_t)row * NHID);
        float xf[4] = {__uint_as_float(fx.x << 16), __uint_as_float(fx.x & 0xFFFF0000u),
                       __uint_as_float(fx.y << 16), __uint_as_float(fx.y & 0xFFFF0000u)};

        float sum = xf[0] + xf[1] + xf[2] + xf[3] + ax + ay + az + aw;
        #pragma unroll
        for (int m = 1; m < 64; m <<= 1) sum += __shfl_xor(sum, m, 64);
        const float mean = sum * (1.f / 512.f);

        float sq = 0.f;
        #pragma unroll
        for (int jj = 0; jj < 4; ++jj) { const float d = xf[jj] - mean; sq += d * d; }
        { float d; d = ax - mean; sq += d * d; d = ay - mean; sq += d * d;
          d = az - mean; sq += d * d; d = aw - mean; sq += d * d; }
        #pragma unroll
        for (int m = 1; m < 64; m <<= 1) sq += __shfl_xor(sq, m, 64);
        const float rstd = rsqrtf(sq * (1.f / 512.f) + LN_EPS);

        const int col = lane * 4;
        const float av[4] = {ax, ay, az, aw};
        ushort4 o0, o1;
        float t0[4], t1[4];
        #pragma unroll
        for (int jj = 0; jj < 4; ++jj) {
            t0[jj] = fmaxf((xf[jj] - mean) * rstd * g[col + jj] + be[col + jj], 0.f);
            t1[jj] = fmaxf((av[jj] - mean) * rstd * g[256 + col + jj] + be[256 + col + jj], 0.f);
        }
        o0.x = bf16_rne(t0[0]); o0.y = bf16_rne(t0[1]); o0.z = bf16_rne(t0[2]); o0.w = bf16_rne(t0[3]);
        o1.x = bf16_rne(t1[0]); o1.y = bf16_rne(t1[1]); o1.z = bf16_rne(t1[2]); o1.w = bf16_rne(t1[3]);
        *(ushort4*)&out0[(size_t)row * NHID + col] = o0;
        *(ushort4*)&out1[(size_t)row * NHID + col] = o1;
    } else {
        ushort4 o;
        o.x = bf16_rne(fmaxf(ax, 0.f)); o.y = bf16_rne(fmaxf(ay, 0.f));
        o.z = bf16_rne(fmaxf(az, 0.f)); o.w = bf16_rne(fmaxf(aw, 0.f));
        *(ushort4*)&out0[(size_t)row * NHID + lane * 4] = o;
    }
}

// ---------------------------------------------------------------------------
extern "C" void kernel_launch(void* const* d_in, const int* in_sizes, int n_in,
                              void* d_out, int out_size, void* d_ws, size_t ws_size,
                              hipStream_t stream)
{
    const float* x    = (const float*)d_in[0];
    const int*   rows = (const int*)  d_in[1];
    const int*   cols = (const int*)  d_in[2];
    const float* vals = (const float*)d_in[3];
    const float* W0   = (const float*)d_in[4];
    const float* b0   = (const float*)d_in[5];
    const float* g0   = (const float*)d_in[6];
    const float* be0  = (const float*)d_in[7];
    const float* W1   = (const float*)d_in[8];
    const float* b1   = (const float*)d_in[9];
    const float* W2   = (const float*)d_in[10];
    const float* b2   = (const float*)d_in[11];
    const float* g2   = (const float*)d_in[12];
    const float* be2  = (const float*)d_in[13];
    const float* W3   = (const float*)d_in[14];
    const float* b3   = (const float*)d_in[15];
    const float* Wout = (const float*)d_in[16];
    const float* bout = (const float*)d_in[17];
    float* out = (float*)d_out;

    // ---- workspace carve ----
    char* wsb = (char*)d_ws;
    size_t off = 0;
    auto carve = [&](size_t bytes) { void* p = wsb + off; off += (bytes + 255) & ~(size_t)255; return p; };
    int*    rowstart = (int*)   carve((size_t)4 * (N_NODES + 1) * 4);
    int*    bcur     = (int*)   carve((size_t)4 * NB * 4);
    int2*   cpk      = (int2*)  carve((size_t)4 * E_EDGES * 8);
    int2*   est      = (int2*)  carve((size_t)4 * NB * CAPB * 8);
    ushort* Xb       = (ushort*)carve((size_t)N_NODES * NFEAT * 2);   // bf16 x
    ushort* F        = (ushort*)carve((size_t)N_NODES * NHID * 2);    // feat
    ushort* P        = (ushort*)carve((size_t)N_NODES * NHID * 2);    // LN feat half
    ushort* Q        = (ushort*)carve((size_t)N_NODES * NHID * 2);    // LN agg half
    ushort* G        = (ushort*)carve((size_t)N_NODES * NHID * 2);    // GCN lin out
    ushort* H        = (ushort*)carve((size_t)N_NODES * NHID * 2);    // GCN relu(agg)
    ushort* W0T = (ushort*)carve((size_t)256 * 512 * 2);
    ushort* W1T = (ushort*)carve((size_t)256 * 512 * 2);
    ushort* W2T = (ushort*)carve((size_t)256 * 256 * 2);
    ushort* W3T = (ushort*)carve((size_t)256 * 512 * 2);
    ushort* WoT = (ushort*)carve((size_t)128 * 256 * 2);
    carve(131072);   // guard pad (gload A-tail overreads)

    const dim3 blk(256);
    const dim3 blkg(512);
    const dim3 g_gemm(391, 2);
    const dim3 g_head(391, 1);
    const dim3 g_bin((E_EDGES + CHUNKA - 1) / CHUNKA, 4);   // (131, 4)
    const dim3 g_sort(NB, 4);                               // (196, 4)
    const int  row_blocks  = (N_NODES * 64 + 255) / 256;    // 12500
    const int  prep_blocks = (PREP_TOTAL + 255) / 256;      // 14424

    // ---- prep (weights + xconv + bcur zero), then CSR build ----
    prep_kernel<<<prep_blocks, blk, 0, stream>>>(W0, W1, W2, W3, Wout, x,
                                                 W0T, W1T, W2T, W3T, WoT, Xb, bcur);
    bin_kernel<<<g_bin, blk, 0, stream>>>(rows, cols, vals, bcur, est);
    sort_kernel<<<g_sort, blk, 0, stream>>>(bcur, est, cpk, rowstart);

    const int* rs0 = rowstart;
    const int* rs1 = rowstart + (N_NODES + 1);
    const int* rs2 = rowstart + 2 * (N_NODES + 1);
    const int* rs3 = rowstart + 3 * (N_NODES + 1);
    const int2* c0 = cpk;
    const int2* c1 = cpk + E_EDGES;
    const int2* c2 = cpk + 2 * (size_t)E_EDGES;
    const int2* c3 = cpk + 3 * (size_t)E_EDGES;

    // ---- layer 0: GraphSage(512->256): Xb -> F; spmm+LN -> P,Q ----
    gemm_mfma_bf16<0,1><<<g_gemm, blkg, 0, stream>>>(Xb, Xb, 512, 512, W0T, b0, nullptr, F, N_NODES, 256);
    spmm_kernel<1><<<row_blocks, blk, 0, stream>>>(rs0, c0, F, P, Q, g0, be0);

    // ---- layer 1: GCN(concat [P|Q] 512->256) -> G; spmm+relu -> H ----
    gemm_mfma_bf16<0,1><<<g_gemm, blkg, 0, stream>>>(P, Q, 256, 512, W1T, b1, nullptr, G, N_NODES, 256);
    spmm_kernel<0><<<row_blocks, blk, 0, stream>>>(rs1, c1, G, H, nullptr, nullptr, nullptr);

    // ---- layer 2: GraphSage(256->256): H -> F; spmm+LN -> P,Q ----
    gemm_mfma_bf16<0,1><<<g_gemm, blkg, 0, stream>>>(H, H, 256, 256, W2T, b2, nullptr, F, N_NODES, 256);
    spmm_kernel<1><<<row_blocks, blk, 0, stream>>>(rs2, c2, F, P, Q, g2, be2);

    // ---- layer 3: GCN(concat [P|Q] 512->256) -> G; spmm+relu -> H ----
    gemm_mfma_bf16<0,1><<<g_gemm, blkg, 0, stream>>>(P, Q, 256, 512, W3T, b3, nullptr, G, N_NODES, 256);
    spmm_kernel<0><<<row_blocks, blk, 0, stream>>>(rs3, c3, G, H, nullptr, nullptr, nullptr);

    // ---- output head: H @ WoT + bout -> out (fp32) ----
    gemm_mfma_bf16<1,0><<<g_head, blkg, 0, stream>>>(H, H, 256, 256, WoT, bout, out, nullptr, N_NODES, 100);
}

// Round 13
// 470.487 us; speedup vs baseline: 1.2262x; 1.0297x over previous
//
#include <hip/hip_runtime.h>

#define N_NODES 50000
#define E_EDGES 800000
#define NFEAT   512
#define NHID    256
#define NCLS    100
#define LN_EPS  1e-5f

#define NB     196     // row buckets of 256 rows
#define CHUNKA 6144    // edges per bin-pass block
#define CAPB   6656    // slots per bucket (exp 4096, +40 sigma)

// prep_kernel section sizes (derived, not hard-coded)
#define WT_TOTAL  (256*512 + 256*512 + 256*256 + 256*512 + 128*256)   // 491520
#define XC_TOTAL  (N_NODES * NFEAT / 8)                               // 3200000
#define PREP_TOTAL (WT_TOTAL + XC_TOTAL + 4 * NB)

typedef __attribute__((ext_vector_type(8))) short bf16x8;
typedef __attribute__((ext_vector_type(4))) float f32x4;

__device__ __forceinline__ ushort bf16_rne(float x) {
    unsigned u = __float_as_uint(x);
    unsigned r = u + 0x7FFFu + ((u >> 16) & 1u);
    return (ushort)(r >> 16);
}
__device__ __forceinline__ float bf16_to_f(ushort h) {
    return __uint_as_float(((unsigned)h) << 16);
}

// async global->LDS, 16 B per lane; LDS dest = wave-uniform base + lane*16
__device__ __forceinline__ void gload16(const void* g, void* l) {
    __builtin_amdgcn_global_load_lds(
        (const __attribute__((address_space(1))) unsigned int*)g,
        (__attribute__((address_space(3))) unsigned int*)l, 16, 0, 0);
}

// ---------------------------------------------------------------------------
// prep: all 5 weight transposes + x fp32->bf16 + bcur zeroing, one launch.
// ---------------------------------------------------------------------------
__global__ __launch_bounds__(256)
void prep_kernel(const float* __restrict__ W0, const float* __restrict__ W1,
                 const float* __restrict__ W2, const float* __restrict__ W3,
                 const float* __restrict__ Wo, const float* __restrict__ x,
                 ushort* __restrict__ W0T, ushort* __restrict__ W1T,
                 ushort* __restrict__ W2T, ushort* __restrict__ W3T,
                 ushort* __restrict__ WoT, ushort* __restrict__ Xb,
                 int* __restrict__ bcur)
{
    int idx = blockIdx.x * 256 + threadIdx.x;
    if (idx < WT_TOTAL) {   // weight transposes
        const float* W; ushort* WT; int K, Nc;
        if      (idx < 131072) { W = W0; WT = W0T; K = 512; Nc = 256; }
        else if (idx < 262144) { idx -= 131072; W = W1; WT = W1T; K = 512; Nc = 256; }
        else if (idx < 327680) { idx -= 262144; W = W2; WT = W2T; K = 256; Nc = 256; }
        else if (idx < 458752) { idx -= 327680; W = W3; WT = W3T; K = 512; Nc = 256; }
        else                   { idx -= 458752; W = Wo; WT = WoT; K = 256; Nc = 100; }
        const int n = idx / K, k = idx - n * K;
        WT[idx] = bf16_rne((n < Nc) ? W[(size_t)k * Nc + n] : 0.f);
        return;
    }
    idx -= WT_TOTAL;
    if (idx < XC_TOTAL) {   // xconv: 8 elems/thread over N*NFEAT
        const float4 v0 = ((const float4*)x)[idx * 2];
        const float4 v1 = ((const float4*)x)[idx * 2 + 1];
        bf16x8 h;
        h[0] = (short)bf16_rne(v0.x); h[1] = (short)bf16_rne(v0.y);
        h[2] = (short)bf16_rne(v0.z); h[3] = (short)bf16_rne(v0.w);
        h[4] = (short)bf16_rne(v1.x); h[5] = (short)bf16_rne(v1.y);
        h[6] = (short)bf16_rne(v1.z); h[7] = (short)bf16_rne(v1.w);
        *(bf16x8*)&Xb[idx * 8] = h;
        return;
    }
    idx -= XC_TOTAL;
    if (idx < 4 * NB) bcur[idx] = 0;
}

// ---------------------------------------------------------------------------
// bf16 MFMA GEMM: 128x128 tile, BK=32, 512 thr = 8 waves (2m x 4n), wave tile
// 64x32. Double-buffered LDS, prefetch-before-compute, 1 barrier/step,
// XOR-swizzled gload source + ds_read.
// SWZ=1: 1-D grid with pair-colocating swizzle so the two column-tiles (y=0,1)
// of one row-block get linear ids differing by 8 -> same XCD (round-robin %8)
// -> second tile's A-read hits that XCD's L2 (halves A fetch).
// ---------------------------------------------------------------------------
template<int SWZ, int WF32, int WBF>
__global__ __launch_bounds__(512)
void gemm_mfma_bf16(const ushort* __restrict__ A1, const ushort* __restrict__ A2,
                    int K1, int K, const ushort* __restrict__ BT,
                    const float* __restrict__ bias, float* __restrict__ C,
                    ushort* __restrict__ Cbf, int M, int Nc)
{
    __shared__ __align__(16) ushort Ah[2][128 * 32];
    __shared__ __align__(16) ushort Bh[2][128 * 32];

    int bx, by;
    if (SWZ) {
        const int bid = blockIdx.x;
        const int g = bid >> 4;            // group of 16 linear ids
        const int r = bid & 15;
        bx = g * 8 + (r & 7);              // row-tile
        by = r >> 3;                       // column-tile 0/1
        if (bx >= (M + 127) / 128) return; // pad blocks
    } else {
        bx = blockIdx.x;
        by = blockIdx.y;
    }

    const int tid = threadIdx.x;
    const int bm  = bx * 128;
    const int bn  = by * 128;
    const int w   = tid >> 6;          // wave 0..7
    const int l   = tid & 63;
    const int wm  = (w >> 2) * 64;     // 0 / 64
    const int wn  = (w & 3) * 32;      // 0,32,64,96
    const int fr  = l & 15;
    const int fq  = l >> 4;

    const int gro = l >> 2;                        // 0..15
    const int gch = ((l & 3) ^ (gro & 3)) * 8;     // swizzled ushort offset
    const int ldsbase = (16 * w) * 32;             // ushorts

    f32x4 acc[4][2];
    #pragma unroll
    for (int i = 0; i < 4; ++i) {
        acc[i][0] = (f32x4){0.f, 0.f, 0.f, 0.f};
        acc[i][1] = (f32x4){0.f, 0.f, 0.f, 0.f};
    }

    const int K2 = K - K1;
    const int NS = K / 32;

    auto stage = [&](int s, int b) {
        const int k0 = s * 32;
        gload16(&BT[(size_t)(bn + 16 * w + gro) * K + k0 + gch], &Bh[b][ldsbase]);
        const ushort* asrc;
        if (k0 < K1) asrc = &A1[(size_t)(bm + 16 * w + gro) * K1 + k0 + gch];
        else         asrc = &A2[(size_t)(bm + 16 * w + gro) * K2 + (k0 - K1) + gch];
        gload16(asrc, &Ah[b][ldsbase]);
    };

    stage(0, 0);
    __syncthreads();

    int cur = 0;
    for (int s = 0; s < NS; ++s) {
        if (s + 1 < NS) stage(s + 1, cur ^ 1);   // prefetch overlaps compute

        bf16x8 bf[2];
        #pragma unroll
        for (int nf = 0; nf < 2; ++nf) {
            const int r = wn + nf * 16 + fr;
            bf[nf] = *(const bf16x8*)&Bh[cur][r * 32 + ((fq ^ (r & 3)) * 8)];
        }
        #pragma unroll
        for (int mf = 0; mf < 4; ++mf) {
            const int r = wm + mf * 16 + fr;
            const bf16x8 af = *(const bf16x8*)&Ah[cur][r * 32 + ((fq ^ (r & 3)) * 8)];
            acc[mf][0] = __builtin_amdgcn_mfma_f32_16x16x32_bf16(af, bf[0], acc[mf][0], 0, 0, 0);
            acc[mf][1] = __builtin_amdgcn_mfma_f32_16x16x32_bf16(af, bf[1], acc[mf][1], 0, 0, 0);
        }
        __syncthreads();
        cur ^= 1;
    }

    #pragma unroll
    for (int mf = 0; mf < 4; ++mf) {
        #pragma unroll
        for (int r = 0; r < 4; ++r) {
            const int row = bm + wm + mf * 16 + fq * 4 + r;
            if (row >= M) continue;
            #pragma unroll
            for (int nf = 0; nf < 2; ++nf) {
                const int col = bn + wn + nf * 16 + fr;
                if (col < Nc) {
                    const float v = acc[mf][nf][r] + bias[col];
                    if (WF32) C[(size_t)row * Nc + col] = v;
                    if (WBF)  Cbf[(size_t)row * Nc + col] = bf16_rne(v);
                }
            }
        }
    }
}

// ---------------------------------------------------------------------------
// CSR build: bin -> sort (sort computes its bucket base inline, writes rowstart)
// ---------------------------------------------------------------------------
__global__ __launch_bounds__(256)
void bin_kernel(const int* __restrict__ rows, const int* __restrict__ cols,
                const float* __restrict__ vals, int* __restrict__ bcur,
                int2* __restrict__ est)
{
    __shared__ int cnt[NB];
    __shared__ int scn[256];
    __shared__ int cstart[NB];
    __shared__ int ccur[NB];
    __shared__ int garr[NB];
    __shared__ __align__(16) int2 buf[CHUNKA];

    const int a  = blockIdx.y;
    const int e0 = blockIdx.x * CHUNKA;
    const int n  = min(CHUNKA, E_EDGES - e0);
    const int t  = threadIdx.x;
    const int*   rp = rows + (size_t)a * E_EDGES + e0;
    const int*   cp = cols + (size_t)a * E_EDGES + e0;
    const float* vp = vals + (size_t)a * E_EDGES + e0;

    if (t < NB) cnt[t] = 0;
    __syncthreads();
    for (int i = t; i < n; i += 256) atomicAdd(&cnt[((unsigned)rp[i]) >> 8], 1);
    __syncthreads();

    scn[t] = (t < NB) ? cnt[t] : 0;
    __syncthreads();
    for (int off = 1; off < 256; off <<= 1) {
        const int v = (t >= off) ? scn[t - off] : 0;
        __syncthreads();
        scn[t] += v;
        __syncthreads();
    }
    if (t < NB) {
        const int ex = scn[t] - cnt[t];
        cstart[t] = ex;
        ccur[t]   = ex;
        garr[t]   = atomicAdd(&bcur[a * NB + t], cnt[t]);
    }
    __syncthreads();

    for (int i = t; i < n; i += 256) {
        const unsigned r = (unsigned)rp[i];
        const int b = r >> 8;
        const int p = atomicAdd(&ccur[b], 1);
        buf[p] = make_int2((int)((r << 16) | (unsigned)cp[i]), __float_as_int(vp[i]));
    }
    __syncthreads();

    for (int i = t; i < n; i += 256) {
        const int2 en = buf[i];
        const int b = ((unsigned)en.x) >> 24;
        const int slot = garr[b] + (i - cstart[b]);
        if (slot < CAPB)
            est[((size_t)(a * NB + b)) * CAPB + slot] = en;
    }
}

__global__ __launch_bounds__(256)
void sort_kernel(const int* __restrict__ bcur, const int2* __restrict__ est,
                 int2* __restrict__ cpk, int* __restrict__ rowstart)
{
    __shared__ __align__(16) int2 sbuf[CAPB];
    __shared__ __align__(16) int2 obuf[CAPB];
    __shared__ int cnt[256];
    __shared__ int scn[256];
    __shared__ int cur[256];

    const int a = blockIdx.y;
    const int b = blockIdx.x;
    const int t = threadIdx.x;
    const int nb = min(bcur[a * NB + b], CAPB);
    const int2* ei = est + ((size_t)(a * NB + b)) * CAPB;

    // bucket base bb = sum_{i<b} bcur[a*NB+i]  (block tree-reduce, b<=195)
    scn[t] = (t < b) ? bcur[a * NB + t] : 0;
    __syncthreads();
    for (int o = 128; o > 0; o >>= 1) {
        if (t < o) scn[t] += scn[t + o];
        __syncthreads();
    }
    const int bb = scn[0];
    __syncthreads();

    for (int i = t; i < nb; i += 256) sbuf[i] = ei[i];
    cnt[t] = 0;
    __syncthreads();
    for (int i = t; i < nb; i += 256)
        atomicAdd(&cnt[(((unsigned)sbuf[i].x) >> 16) & 255], 1);
    __syncthreads();

    scn[t] = cnt[t];
    __syncthreads();
    for (int off = 1; off < 256; off <<= 1) {
        const int v = (t >= off) ? scn[t - off] : 0;
        __syncthreads();
        scn[t] += v;
        __syncthreads();
    }
    const int excl = scn[t] - cnt[t];
    cur[t] = excl;

    const int r0 = b << 8;
    if (r0 + t < N_NODES)
        rowstart[(size_t)a * (N_NODES + 1) + r0 + t] = bb + excl;
    if (b == NB - 1 && t == 0)
        rowstart[(size_t)a * (N_NODES + 1) + N_NODES] = E_EDGES;
    __syncthreads();

    for (int i = t; i < nb; i += 256) {
        const int2 en = sbuf[i];
        const int r = (((unsigned)en.x) >> 16) & 255;
        const int p = atomicAdd(&cur[r], 1);
        obuf[p] = make_int2(en.x & 0xFFFF, en.y);
    }
    __syncthreads();

    int2* co = cpk + (size_t)a * E_EDGES + bb;
    for (int i = t; i < nb; i += 256) co[i] = obuf[i];
}

// ---------------------------------------------------------------------------
// SpMM gather over CSR, scalar edge loads (wave-uniform -> s_load broadcast).
// One wave per row; lane holds 4 bf16 (8 B). Full 16-batches unguarded.
// LNFUSE=1: fused LayerNorm over concat [feat[row] | agg] + affine + relu.
// ---------------------------------------------------------------------------
template<int LNFUSE>
__global__ __launch_bounds__(256)
void spmm_kernel(const int* __restrict__ rowstart, const int2* __restrict__ cpk,
                 const ushort* __restrict__ feat, ushort* __restrict__ out0,
                 ushort* __restrict__ out1, const float* __restrict__ g,
                 const float* __restrict__ be)
{
    const int row  = __builtin_amdgcn_readfirstlane((blockIdx.x * 256 + threadIdx.x) >> 6);
    const int lane = threadIdx.x & 63;

    const int s = __builtin_amdgcn_readfirstlane(rowstart[row]);
    const int e = __builtin_amdgcn_readfirstlane(rowstart[row + 1]);

    const ushort* fbase = feat + lane * 4;
    float ax = 0.f, ay = 0.f, az = 0.f, aw = 0.f;

    int j = s;
    for (; j + 16 <= e; j += 16) {
        #pragma unroll
        for (int q = 0; q < 16; ++q) {
            const int2 ev = cpk[j + q];            // scalar load + broadcast
            const float v = __int_as_float(ev.y);
            const uint2 f = *(const uint2*)(fbase + (size_t)ev.x * NHID);
            ax += v * __uint_as_float(f.x << 16);
            ay += v * __uint_as_float(f.x & 0xFFFF0000u);
            az += v * __uint_as_float(f.y << 16);
            aw += v * __uint_as_float(f.y & 0xFFFF0000u);
        }
    }
    for (; j < e; ++j) {
        const int2 ev = cpk[j];
        const float v = __int_as_float(ev.y);
        const uint2 f = *(const uint2*)(fbase + (size_t)ev.x * NHID);
        ax += v * __uint_as_float(f.x << 16);
        ay += v * __uint_as_float(f.x & 0xFFFF0000u);
        az += v * __uint_as_float(f.y << 16);
        aw += v * __uint_as_float(f.y & 0xFFFF0000u);
    }

    if (LNFUSE) {
        const uint2 fx = *(const uint2*)(fbase + (size_t)row * NHID);
        float xf[4] = {__uint_as_float(fx.x << 16), __uint_as_float(fx.x & 0xFFFF0000u),
                       __uint_as_float(fx.y << 16), __uint_as_float(fx.y & 0xFFFF0000u)};

        float sum = xf[0] + xf[1] + xf[2] + xf[3] + ax + ay + az + aw;
        #pragma unroll
        for (int m = 1; m < 64; m <<= 1) sum += __shfl_xor(sum, m, 64);
        const float mean = sum * (1.f / 512.f);

        float sq = 0.f;
        #pragma unroll
        for (int jj = 0; jj < 4; ++jj) { const float d = xf[jj] - mean; sq += d * d; }
        { float d; d = ax - mean; sq += d * d; d = ay - mean; sq += d * d;
          d = az - mean; sq += d * d; d = aw - mean; sq += d * d; }
        #pragma unroll
        for (int m = 1; m < 64; m <<= 1) sq += __shfl_xor(sq, m, 64);
        const float rstd = rsqrtf(sq * (1.f / 512.f) + LN_EPS);

        const int col = lane * 4;
        const float av[4] = {ax, ay, az, aw};
        ushort4 o0, o1;
        float t0[4], t1[4];
        #pragma unroll
        for (int jj = 0; jj < 4; ++jj) {
            t0[jj] = fmaxf((xf[jj] - mean) * rstd * g[col + jj] + be[col + jj], 0.f);
            t1[jj] = fmaxf((av[jj] - mean) * rstd * g[256 + col + jj] + be[256 + col + jj], 0.f);
        }
        o0.x = bf16_rne(t0[0]); o0.y = bf16_rne(t0[1]); o0.z = bf16_rne(t0[2]); o0.w = bf16_rne(t0[3]);
        o1.x = bf16_rne(t1[0]); o1.y = bf16_rne(t1[1]); o1.z = bf16_rne(t1[2]); o1.w = bf16_rne(t1[3]);
        *(ushort4*)&out0[(size_t)row * NHID + col] = o0;
        *(ushort4*)&out1[(size_t)row * NHID + col] = o1;
    } else {
        ushort4 o;
        o.x = bf16_rne(fmaxf(ax, 0.f)); o.y = bf16_rne(fmaxf(ay, 0.f));
        o.z = bf16_rne(fmaxf(az, 0.f)); o.w = bf16_rne(fmaxf(aw, 0.f));
        *(ushort4*)&out0[(size_t)row * NHID + lane * 4] = o;
    }
}

// ---------------------------------------------------------------------------
extern "C" void kernel_launch(void* const* d_in, const int* in_sizes, int n_in,
                              void* d_out, int out_size, void* d_ws, size_t ws_size,
                              hipStream_t stream)
{
    const float* x    = (const float*)d_in[0];
    const int*   rows = (const int*)  d_in[1];
    const int*   cols = (const int*)  d_in[2];
    const float* vals = (const float*)d_in[3];
    const float* W0   = (const float*)d_in[4];
    const float* b0   = (const float*)d_in[5];
    const float* g0   = (const float*)d_in[6];
    const float* be0  = (const float*)d_in[7];
    const float* W1   = (const float*)d_in[8];
    const float* b1   = (const float*)d_in[9];
    const float* W2   = (const float*)d_in[10];
    const float* b2   = (const float*)d_in[11];
    const float* g2   = (const float*)d_in[12];
    const float* be2  = (const float*)d_in[13];
    const float* W3   = (const float*)d_in[14];
    const float* b3   = (const float*)d_in[15];
    const float* Wout = (const float*)d_in[16];
    const float* bout = (const float*)d_in[17];
    float* out = (float*)d_out;

    // ---- workspace carve ----
    char* wsb = (char*)d_ws;
    size_t off = 0;
    auto carve = [&](size_t bytes) { void* p = wsb + off; off += (bytes + 255) & ~(size_t)255; return p; };
    int*    rowstart = (int*)   carve((size_t)4 * (N_NODES + 1) * 4);
    int*    bcur     = (int*)   carve((size_t)4 * NB * 4);
    int2*   cpk      = (int2*)  carve((size_t)4 * E_EDGES * 8);
    int2*   est      = (int2*)  carve((size_t)4 * NB * CAPB * 8);
    ushort* Xb       = (ushort*)carve((size_t)N_NODES * NFEAT * 2);   // bf16 x
    ushort* F        = (ushort*)carve((size_t)N_NODES * NHID * 2);    // feat
    ushort* P        = (ushort*)carve((size_t)N_NODES * NHID * 2);    // LN feat half
    ushort* Q        = (ushort*)carve((size_t)N_NODES * NHID * 2);    // LN agg half
    ushort* G        = (ushort*)carve((size_t)N_NODES * NHID * 2);    // GCN lin out
    ushort* H        = (ushort*)carve((size_t)N_NODES * NHID * 2);    // GCN relu(agg)
    ushort* W0T = (ushort*)carve((size_t)256 * 512 * 2);
    ushort* W1T = (ushort*)carve((size_t)256 * 512 * 2);
    ushort* W2T = (ushort*)carve((size_t)256 * 256 * 2);
    ushort* W3T = (ushort*)carve((size_t)256 * 512 * 2);
    ushort* WoT = (ushort*)carve((size_t)128 * 256 * 2);
    carve(131072);   // guard pad (gload A-tail overreads)

    const dim3 blk(256);
    const dim3 blkg(512);
    const dim3 g_gemm(784);        // 49 groups x 16, pair-swizzled (2 pad blocks)
    const dim3 g_head(391, 1);
    const dim3 g_bin((E_EDGES + CHUNKA - 1) / CHUNKA, 4);   // (131, 4)
    const dim3 g_sort(NB, 4);                               // (196, 4)
    const int  row_blocks  = (N_NODES * 64 + 255) / 256;    // 12500
    const int  prep_blocks = (PREP_TOTAL + 255) / 256;      // 14424

    // ---- prep (weights + xconv + bcur zero), then CSR build ----
    prep_kernel<<<prep_blocks, blk, 0, stream>>>(W0, W1, W2, W3, Wout, x,
                                                 W0T, W1T, W2T, W3T, WoT, Xb, bcur);
    bin_kernel<<<g_bin, blk, 0, stream>>>(rows, cols, vals, bcur, est);
    sort_kernel<<<g_sort, blk, 0, stream>>>(bcur, est, cpk, rowstart);

    const int* rs0 = rowstart;
    const int* rs1 = rowstart + (N_NODES + 1);
    const int* rs2 = rowstart + 2 * (N_NODES + 1);
    const int* rs3 = rowstart + 3 * (N_NODES + 1);
    const int2* c0 = cpk;
    const int2* c1 = cpk + E_EDGES;
    const int2* c2 = cpk + 2 * (size_t)E_EDGES;
    const int2* c3 = cpk + 3 * (size_t)E_EDGES;

    // ---- layer 0: GraphSage(512->256): Xb -> F; spmm+LN -> P,Q ----
    gemm_mfma_bf16<1,0,1><<<g_gemm, blkg, 0, stream>>>(Xb, Xb, 512, 512, W0T, b0, nullptr, F, N_NODES, 256);
    spmm_kernel<1><<<row_blocks, blk, 0, stream>>>(rs0, c0, F, P, Q, g0, be0);

    // ---- layer 1: GCN(concat [P|Q] 512->256) -> G; spmm+relu -> H ----
    gemm_mfma_bf16<1,0,1><<<g_gemm, blkg, 0, stream>>>(P, Q, 256, 512, W1T, b1, nullptr, G, N_NODES, 256);
    spmm_kernel<0><<<row_blocks, blk, 0, stream>>>(rs1, c1, G, H, nullptr, nullptr, nullptr);

    // ---- layer 2: GraphSage(256->256): H -> F; spmm+LN -> P,Q ----
    gemm_mfma_bf16<1,0,1><<<g_gemm, blkg, 0, stream>>>(H, H, 256, 256, W2T, b2, nullptr, F, N_NODES, 256);
    spmm_kernel<1><<<row_blocks, blk, 0, stream>>>(rs2, c2, F, P, Q, g2, be2);

    // ---- layer 3: GCN(concat [P|Q] 512->256) -> G; spmm+relu -> H ----
    gemm_mfma_bf16<1,0,1><<<g_gemm, blkg, 0, stream>>>(P, Q, 256, 512, W3T, b3, nullptr, G, N_NODES, 256);
    spmm_kernel<0><<<row_blocks, blk, 0, stream>>>(rs3, c3, G, H, nullptr, nullptr, nullptr);

    // ---- output head: H @ WoT + bout -> out (fp32) ----
    gemm_mfma_bf16<0,1,0><<<g_head, blkg, 0, stream>>>(H, H, 256, 256, WoT, bout, out, nullptr, N_NODES, 100);
}